// Round 6
// baseline (211.757 us; speedup 1.0000x reference)
//
#include <hip/hip_runtime.h>

// Round 5 (resubmit after infra timeout): (a) streaming-copy probe (in -> ws)
// to measure achievable read+write time in-context and warm L3; (b) median
// kernel with ROWS=8, relaxed launch bounds, and a sched_barrier forcing all
// loads in flight.

#define H 512
#define W 512
#define ROWS 8
#define STRIPS (H / ROWS)   // 64

__device__ __forceinline__ float f_min3(float a, float b, float c) { return fminf(fminf(a, b), c); }
__device__ __forceinline__ float f_max3(float a, float b, float c) { return fmaxf(fmaxf(a, b), c); }
__device__ __forceinline__ float f_med3(float a, float b, float c) { return __builtin_amdgcn_fmed3f(a, b, c); }

// ---------------- probe: pure streaming copy, in -> ws ----------------
__global__ __launch_bounds__(256) void probe_copy(const float4* __restrict__ in,
                                                  float4* __restrict__ ws, int n4) {
    int stride = gridDim.x * 256;
    for (int i = blockIdx.x * 256 + threadIdx.x; i < n4; i += stride)
        ws[i] = in[i];
}

// probe fallback if ws is too small: read-only reduce (keeps read-side info)
__global__ __launch_bounds__(256) void probe_read(const float4* __restrict__ in,
                                                  float* __restrict__ ws, int n4) {
    int stride = gridDim.x * 256;
    float s = 0.f;
    for (int i = blockIdx.x * 256 + threadIdx.x; i < n4; i += stride) {
        float4 v = in[i];
        s += v.x + v.y + v.z + v.w;
    }
    if (s == 123456789.0f) ws[0] = s;   // never true for this data; keeps loads live
}

// ---------------- median 3x3 ----------------
__global__ __launch_bounds__(256) void median3x3_kernel(const float* __restrict__ in,
                                                        float* __restrict__ out) {
    int t = blockIdx.x * 256 + threadIdx.x;
    int lane  = t & 63;
    int strip = (t >> 6) & (STRIPS - 1);
    int plane = t >> 12;                 // 96 planes (64 strips * 64 lanes = 4096/plane)

    int ybase = strip * ROWS;
    int xA = lane << 2;                  // dense half 0 (cols lane*4..+3); half 1 at +256
    const float* pbase = in + (size_t)plane * (H * W);

    // Register window: rows ybase-1 .. ybase+ROWS (ROWS+2 rows), two dense halves.
    float A[ROWS + 2][4], B[ROWS + 2][4];
#pragma unroll
    for (int i = 0; i < ROWS + 2; ++i) {
        int yy = ybase + i - 1;
        if (yy >= 0 && yy < H) {         // wave-uniform
            const float* prow = pbase + (size_t)yy * W;
            float4 a = *(const float4*)(prow + xA);
            float4 b = *(const float4*)(prow + 256 + xA);
            A[i][0] = a.x; A[i][1] = a.y; A[i][2] = a.z; A[i][3] = a.w;
            B[i][0] = b.x; B[i][1] = b.y; B[i][2] = b.z; B[i][3] = b.w;
        } else {
#pragma unroll
            for (int j = 0; j < 4; ++j) { A[i][j] = 0.0f; B[i][j] = 0.0f; }
        }
    }
    // Forbid sinking loads into the compute: everything above issues first.
    __builtin_amdgcn_sched_barrier(0);

    // Halos via in-wave shuffles (borders are true zeros; A/B seam broadcast).
    float Al[ROWS + 2], Ar[ROWS + 2], Bl[ROWS + 2], Br[ROWS + 2];
#pragma unroll
    for (int i = 0; i < ROWS + 2; ++i) {
        float al = __shfl_up(A[i][3], 1);
        float ar = __shfl_down(A[i][0], 1);
        float bl = __shfl_up(B[i][3], 1);
        float br = __shfl_down(B[i][0], 1);
        float b0w0  = __shfl(B[i][0], 0);    // col 256 (lane 63's A-right)
        float a3w63 = __shfl(A[i][3], 63);   // col 255 (lane 0's B-left)
        Al[i] = (lane == 0)  ? 0.0f  : al;
        Ar[i] = (lane == 63) ? b0w0  : ar;
        Bl[i] = (lane == 0)  ? a3w63 : bl;
        Br[i] = (lane == 63) ? 0.0f  : br;
    }

    float* obase = out + (size_t)plane * (H * W) + (size_t)ybase * W + xA;
#pragma unroll
    for (int r = 0; r < ROWS; ++r) {
        float resA[4], resB[4];
#pragma unroll
        for (int j = 0; j < 4; ++j) {
            float a0 = (j == 0) ? Al[r]     : A[r][j - 1];
            float a1 = A[r][j];
            float a2 = (j == 3) ? Ar[r]     : A[r][j + 1];
            float b0 = (j == 0) ? Al[r + 1] : A[r + 1][j - 1];
            float b1 = A[r + 1][j];
            float b2 = (j == 3) ? Ar[r + 1] : A[r + 1][j + 1];
            float c0 = (j == 0) ? Al[r + 2] : A[r + 2][j - 1];
            float c1 = A[r + 2][j];
            float c2 = (j == 3) ? Ar[r + 2] : A[r + 2][j + 1];
            float l0 = f_min3(a0, a1, a2), m0 = f_med3(a0, a1, a2), h0 = f_max3(a0, a1, a2);
            float l1 = f_min3(b0, b1, b2), m1 = f_med3(b0, b1, b2), h1 = f_max3(b0, b1, b2);
            float l2 = f_min3(c0, c1, c2), m2 = f_med3(c0, c1, c2), h2 = f_max3(c0, c1, c2);
            resA[j] = f_med3(f_max3(l0, l1, l2), f_med3(m0, m1, m2), f_min3(h0, h1, h2));

            float d0 = (j == 0) ? Bl[r]     : B[r][j - 1];
            float d1 = B[r][j];
            float d2 = (j == 3) ? Br[r]     : B[r][j + 1];
            float e0 = (j == 0) ? Bl[r + 1] : B[r + 1][j - 1];
            float e1 = B[r + 1][j];
            float e2 = (j == 3) ? Br[r + 1] : B[r + 1][j + 1];
            float g0 = (j == 0) ? Bl[r + 2] : B[r + 2][j - 1];
            float g1 = B[r + 2][j];
            float g2 = (j == 3) ? Br[r + 2] : B[r + 2][j + 1];
            float l3 = f_min3(d0, d1, d2), m3 = f_med3(d0, d1, d2), h3 = f_max3(d0, d1, d2);
            float l4 = f_min3(e0, e1, e2), m4 = f_med3(e0, e1, e2), h4 = f_max3(e0, e1, e2);
            float l5 = f_min3(g0, g1, g2), m5 = f_med3(g0, g1, g2), h5 = f_max3(g0, g1, g2);
            resB[j] = f_med3(f_max3(l3, l4, l5), f_med3(m3, m4, m5), f_min3(h3, h4, h5));
        }
        float* orow = obase + (size_t)r * W;
        *(float4*)orow         = make_float4(resA[0], resA[1], resA[2], resA[3]);
        *(float4*)(orow + 256) = make_float4(resB[0], resB[1], resB[2], resB[3]);
    }
}

extern "C" void kernel_launch(void* const* d_in, const int* in_sizes, int n_in,
                              void* d_out, int out_size, void* d_ws, size_t ws_size,
                              hipStream_t stream) {
    const float* x = (const float*)d_in[0];
    float* out = (float*)d_out;

    // ---- probe first (also warms L3 with the input) ----
    int n4 = out_size / 4;                         // 6,291,456 float4s
    size_t in_bytes = (size_t)out_size * 4;
    if (ws_size >= in_bytes) {
        probe_copy<<<dim3(2048), dim3(256), 0, stream>>>(
            (const float4*)x, (float4*)d_ws, n4);
    } else {
        probe_read<<<dim3(2048), dim3(256), 0, stream>>>(
            (const float4*)x, (float*)d_ws, n4);
    }

    // ---- median filter ----
    // out_size = 32*3*512*512; each thread: 8 cols * 8 rows = 64 elems.
    int threads_total = out_size / 64;   // 393,216
    int blocks = threads_total / 256;    // 1,536
    median3x3_kernel<<<dim3(blocks), dim3(256), 0, stream>>>(x, out);
}

// Round 9
// 178.258 us; speedup vs baseline: 1.1879x; 1.1879x over previous
//
#include <hip/hip_runtime.h>

// 3x3 median filter, zero-padded, (32,3,512,512) fp32.
// One wave spans a full 512-col row via two dense half-rows
// (cols lane*4 and 256+lane*4); all loads/stores are dense 16B/lane.
// Horizontal halos via in-wave __shfl; vertical blocking ROWS=8 rows/thread
// (10-row register window), sched_barrier keeps all 20 loads in flight
// before compute. Median-of-9 via sorted-triples identity:
//   med9 = med3( max3(row mins), med3(row meds), min3(row maxes) )
// using single-instruction v_min3/v_med3/v_max3 (exact vs sort[4]).

#define H 512
#define W 512
#define ROWS 8
#define STRIPS (H / ROWS)   // 64

__device__ __forceinline__ float f_min3(float a, float b, float c) { return fminf(fminf(a, b), c); }
__device__ __forceinline__ float f_max3(float a, float b, float c) { return fmaxf(fmaxf(a, b), c); }
__device__ __forceinline__ float f_med3(float a, float b, float c) { return __builtin_amdgcn_fmed3f(a, b, c); }

__global__ __launch_bounds__(256) void median3x3_kernel(const float* __restrict__ in,
                                                        float* __restrict__ out) {
    int t = blockIdx.x * 256 + threadIdx.x;
    int lane  = t & 63;
    int strip = (t >> 6) & (STRIPS - 1);
    int plane = t >> 12;                 // 96 planes

    int ybase = strip * ROWS;
    int xA = lane << 2;                  // dense half 0 (cols lane*4..+3); half 1 at +256
    const float* pbase = in + (size_t)plane * (H * W);

    // Register window: rows ybase-1 .. ybase+ROWS (ROWS+2 rows), two dense halves.
    float A[ROWS + 2][4], B[ROWS + 2][4];
#pragma unroll
    for (int i = 0; i < ROWS + 2; ++i) {
        int yy = ybase + i - 1;
        if (yy >= 0 && yy < H) {         // wave-uniform
            const float* prow = pbase + (size_t)yy * W;
            float4 a = *(const float4*)(prow + xA);
            float4 b = *(const float4*)(prow + 256 + xA);
            A[i][0] = a.x; A[i][1] = a.y; A[i][2] = a.z; A[i][3] = a.w;
            B[i][0] = b.x; B[i][1] = b.y; B[i][2] = b.z; B[i][3] = b.w;
        } else {
#pragma unroll
            for (int j = 0; j < 4; ++j) { A[i][j] = 0.0f; B[i][j] = 0.0f; }
        }
    }
    // Forbid sinking loads into the compute: everything above issues first.
    __builtin_amdgcn_sched_barrier(0);

    // Halos via in-wave shuffles (borders are true zeros; A/B seam broadcast).
    float Al[ROWS + 2], Ar[ROWS + 2], Bl[ROWS + 2], Br[ROWS + 2];
#pragma unroll
    for (int i = 0; i < ROWS + 2; ++i) {
        float al = __shfl_up(A[i][3], 1);
        float ar = __shfl_down(A[i][0], 1);
        float bl = __shfl_up(B[i][3], 1);
        float br = __shfl_down(B[i][0], 1);
        float b0w0  = __shfl(B[i][0], 0);    // col 256 (lane 63's A-right)
        float a3w63 = __shfl(A[i][3], 63);   // col 255 (lane 0's B-left)
        Al[i] = (lane == 0)  ? 0.0f  : al;
        Ar[i] = (lane == 63) ? b0w0  : ar;
        Bl[i] = (lane == 0)  ? a3w63 : bl;
        Br[i] = (lane == 63) ? 0.0f  : br;
    }

    float* obase = out + (size_t)plane * (H * W) + (size_t)ybase * W + xA;
#pragma unroll
    for (int r = 0; r < ROWS; ++r) {
        float resA[4], resB[4];
#pragma unroll
        for (int j = 0; j < 4; ++j) {
            float a0 = (j == 0) ? Al[r]     : A[r][j - 1];
            float a1 = A[r][j];
            float a2 = (j == 3) ? Ar[r]     : A[r][j + 1];
            float b0 = (j == 0) ? Al[r + 1] : A[r + 1][j - 1];
            float b1 = A[r + 1][j];
            float b2 = (j == 3) ? Ar[r + 1] : A[r + 1][j + 1];
            float c0 = (j == 0) ? Al[r + 2] : A[r + 2][j - 1];
            float c1 = A[r + 2][j];
            float c2 = (j == 3) ? Ar[r + 2] : A[r + 2][j + 1];
            float l0 = f_min3(a0, a1, a2), m0 = f_med3(a0, a1, a2), h0 = f_max3(a0, a1, a2);
            float l1 = f_min3(b0, b1, b2), m1 = f_med3(b0, b1, b2), h1 = f_max3(b0, b1, b2);
            float l2 = f_min3(c0, c1, c2), m2 = f_med3(c0, c1, c2), h2 = f_max3(c0, c1, c2);
            resA[j] = f_med3(f_max3(l0, l1, l2), f_med3(m0, m1, m2), f_min3(h0, h1, h2));

            float d0 = (j == 0) ? Bl[r]     : B[r][j - 1];
            float d1 = B[r][j];
            float d2 = (j == 3) ? Br[r]     : B[r][j + 1];
            float e0 = (j == 0) ? Bl[r + 1] : B[r + 1][j - 1];
            float e1 = B[r + 1][j];
            float e2 = (j == 3) ? Br[r + 1] : B[r + 1][j + 1];
            float g0 = (j == 0) ? Bl[r + 2] : B[r + 2][j - 1];
            float g1 = B[r + 2][j];
            float g2 = (j == 3) ? Br[r + 2] : B[r + 2][j + 1];
            float l3 = f_min3(d0, d1, d2), m3 = f_med3(d0, d1, d2), h3 = f_max3(d0, d1, d2);
            float l4 = f_min3(e0, e1, e2), m4 = f_med3(e0, e1, e2), h4 = f_max3(e0, e1, e2);
            float l5 = f_min3(g0, g1, g2), m5 = f_med3(g0, g1, g2), h5 = f_max3(g0, g1, g2);
            resB[j] = f_med3(f_max3(l3, l4, l5), f_med3(m3, m4, m5), f_min3(h3, h4, h5));
        }
        float* orow = obase + (size_t)r * W;
        *(float4*)orow         = make_float4(resA[0], resA[1], resA[2], resA[3]);
        *(float4*)(orow + 256) = make_float4(resB[0], resB[1], resB[2], resB[3]);
    }
}

extern "C" void kernel_launch(void* const* d_in, const int* in_sizes, int n_in,
                              void* d_out, int out_size, void* d_ws, size_t ws_size,
                              hipStream_t stream) {
    const float* x = (const float*)d_in[0];
    float* out = (float*)d_out;

    // out_size = 32*3*512*512; each thread: 8 cols * 8 rows = 64 elems.
    int threads_total = out_size / 64;   // 393,216
    int blocks = threads_total / 256;    // 1,536
    median3x3_kernel<<<dim3(blocks), dim3(256), 0, stream>>>(x, out);
}

// Round 10
// 176.095 us; speedup vs baseline: 1.2025x; 1.0123x over previous
//
#include <hip/hip_runtime.h>

// 3x3 median filter, zero-padded, (32,3,512,512) fp32.
// One wave spans a full 512-col row via two dense half-rows
// (cols lane*4 and 256+lane*4); all loads/stores dense 16B/lane.
// ROWS=8 rows/thread from a 10-row register window.
// Round 10 change: BRANCHLESS loads — row index clamped so all 20 float4
// loads are unconditional (single scheduling region, all in flight),
// out-of-image rows zeroed afterwards via cndmask selects.
// Median-of-9 = med3(max3(row mins), med3(row meds), min3(row maxes))
// over sorted horizontal triples (exact; v_min3/v_med3/v_max3).

#define H 512
#define W 512
#define ROWS 8
#define STRIPS (H / ROWS)   // 64

__device__ __forceinline__ float f_min3(float a, float b, float c) { return fminf(fminf(a, b), c); }
__device__ __forceinline__ float f_max3(float a, float b, float c) { return fmaxf(fmaxf(a, b), c); }
__device__ __forceinline__ float f_med3(float a, float b, float c) { return __builtin_amdgcn_fmed3f(a, b, c); }

__global__ __launch_bounds__(256) void median3x3_kernel(const float* __restrict__ in,
                                                        float* __restrict__ out) {
    int t = blockIdx.x * 256 + threadIdx.x;
    int lane  = t & 63;
    int strip = (t >> 6) & (STRIPS - 1);
    int plane = t >> 12;                 // 96 planes

    int ybase = strip * ROWS;
    int xA = lane << 2;                  // dense half 0 (cols lane*4..+3); half 1 at +256
    const float* pbase = in + (size_t)plane * (H * W);

    // ---- 20 unconditional float4 loads (clamped row index), one region ----
    float4 ra[ROWS + 2], rb[ROWS + 2];
#pragma unroll
    for (int i = 0; i < ROWS + 2; ++i) {
        int yy = ybase + i - 1;
        int yc = min(max(yy, 0), H - 1);           // clamp: always a valid row
        const float* prow = pbase + (size_t)yc * W;
        ra[i] = *(const float4*)(prow + xA);
        rb[i] = *(const float4*)(prow + 256 + xA);
    }
    __builtin_amdgcn_sched_barrier(0);   // loads issue before anything below

    // ---- zero-select invalid rows (branchless; wave-uniform condition) ----
    float A[ROWS + 2][4], B[ROWS + 2][4];
#pragma unroll
    for (int i = 0; i < ROWS + 2; ++i) {
        int yy = ybase + i - 1;
        bool valid = (yy >= 0) && (yy < H);
        A[i][0] = valid ? ra[i].x : 0.0f;
        A[i][1] = valid ? ra[i].y : 0.0f;
        A[i][2] = valid ? ra[i].z : 0.0f;
        A[i][3] = valid ? ra[i].w : 0.0f;
        B[i][0] = valid ? rb[i].x : 0.0f;
        B[i][1] = valid ? rb[i].y : 0.0f;
        B[i][2] = valid ? rb[i].z : 0.0f;
        B[i][3] = valid ? rb[i].w : 0.0f;
    }

    // ---- halos via in-wave shuffles (borders true zeros; A/B seam bcast) ----
    float Al[ROWS + 2], Ar[ROWS + 2], Bl[ROWS + 2], Br[ROWS + 2];
#pragma unroll
    for (int i = 0; i < ROWS + 2; ++i) {
        float al = __shfl_up(A[i][3], 1);
        float ar = __shfl_down(A[i][0], 1);
        float bl = __shfl_up(B[i][3], 1);
        float br = __shfl_down(B[i][0], 1);
        float b0w0  = __shfl(B[i][0], 0);    // col 256 (lane 63's A-right)
        float a3w63 = __shfl(A[i][3], 63);   // col 255 (lane 0's B-left)
        Al[i] = (lane == 0)  ? 0.0f  : al;
        Ar[i] = (lane == 63) ? b0w0  : ar;
        Bl[i] = (lane == 0)  ? a3w63 : bl;
        Br[i] = (lane == 63) ? 0.0f  : br;
    }

    float* obase = out + (size_t)plane * (H * W) + (size_t)ybase * W + xA;
#pragma unroll
    for (int r = 0; r < ROWS; ++r) {
        float resA[4], resB[4];
#pragma unroll
        for (int j = 0; j < 4; ++j) {
            float a0 = (j == 0) ? Al[r]     : A[r][j - 1];
            float a1 = A[r][j];
            float a2 = (j == 3) ? Ar[r]     : A[r][j + 1];
            float b0 = (j == 0) ? Al[r + 1] : A[r + 1][j - 1];
            float b1 = A[r + 1][j];
            float b2 = (j == 3) ? Ar[r + 1] : A[r + 1][j + 1];
            float c0 = (j == 0) ? Al[r + 2] : A[r + 2][j - 1];
            float c1 = A[r + 2][j];
            float c2 = (j == 3) ? Ar[r + 2] : A[r + 2][j + 1];
            float l0 = f_min3(a0, a1, a2), m0 = f_med3(a0, a1, a2), h0 = f_max3(a0, a1, a2);
            float l1 = f_min3(b0, b1, b2), m1 = f_med3(b0, b1, b2), h1 = f_max3(b0, b1, b2);
            float l2 = f_min3(c0, c1, c2), m2 = f_med3(c0, c1, c2), h2 = f_max3(c0, c1, c2);
            resA[j] = f_med3(f_max3(l0, l1, l2), f_med3(m0, m1, m2), f_min3(h0, h1, h2));

            float d0 = (j == 0) ? Bl[r]     : B[r][j - 1];
            float d1 = B[r][j];
            float d2 = (j == 3) ? Br[r]     : B[r][j + 1];
            float e0 = (j == 0) ? Bl[r + 1] : B[r + 1][j - 1];
            float e1 = B[r + 1][j];
            float e2 = (j == 3) ? Br[r + 1] : B[r + 1][j + 1];
            float g0 = (j == 0) ? Bl[r + 2] : B[r + 2][j - 1];
            float g1 = B[r + 2][j];
            float g2 = (j == 3) ? Br[r + 2] : B[r + 2][j + 1];
            float l3 = f_min3(d0, d1, d2), m3 = f_med3(d0, d1, d2), h3 = f_max3(d0, d1, d2);
            float l4 = f_min3(e0, e1, e2), m4 = f_med3(e0, e1, e2), h4 = f_max3(e0, e1, e2);
            float l5 = f_min3(g0, g1, g2), m5 = f_med3(g0, g1, g2), h5 = f_max3(g0, g1, g2);
            resB[j] = f_med3(f_max3(l3, l4, l5), f_med3(m3, m4, m5), f_min3(h3, h4, h5));
        }
        float* orow = obase + (size_t)r * W;
        *(float4*)orow         = make_float4(resA[0], resA[1], resA[2], resA[3]);
        *(float4*)(orow + 256) = make_float4(resB[0], resB[1], resB[2], resB[3]);
    }
}

extern "C" void kernel_launch(void* const* d_in, const int* in_sizes, int n_in,
                              void* d_out, int out_size, void* d_ws, size_t ws_size,
                              hipStream_t stream) {
    const float* x = (const float*)d_in[0];
    float* out = (float*)d_out;

    // out_size = 32*3*512*512; each thread: 8 cols * 8 rows = 64 elems.
    int threads_total = out_size / 64;   // 393,216
    int blocks = threads_total / 256;    // 1,536
    median3x3_kernel<<<dim3(blocks), dim3(256), 0, stream>>>(x, out);
}

// Round 11
// 172.428 us; speedup vs baseline: 1.2281x; 1.0213x over previous
//
#include <hip/hip_runtime.h>

// 3x3 median filter, zero-padded, (32,3,512,512) fp32.
// Round 11: LDS tile staging via __builtin_amdgcn_global_load_lds (16B),
// fire-and-forget reads (no VGPR cost -> deep MLP), then compute from LDS.
// Block = 256 threads stages an 18-row x 512-col tile (rows ybase-1..ybase+16,
// row-clamped; out-of-image rows zero-selected at consume). Each thread
// computes 4 cols x 8 rows via a rolling 3-row sorted-triple window:
//   med9 = med3( max3(row mins), med3(row meds), min3(row maxes) )  (exact)

#define H 512
#define W 512
#define TR 16                      // output rows per block
#define TILE_ROWS (TR + 2)         // 18 staged rows
#define STRIPS (H / TR)            // 32
#define LDS_ELEMS (TILE_ROWS * W)  // 9216 floats = 36864 B
#define STAGE_ROUNDS (LDS_ELEMS / (256 * 4))   // 9

__device__ __forceinline__ float f_min3(float a, float b, float c) { return fminf(fminf(a, b), c); }
__device__ __forceinline__ float f_max3(float a, float b, float c) { return fmaxf(fmaxf(a, b), c); }
__device__ __forceinline__ float f_med3(float a, float b, float c) { return __builtin_amdgcn_fmed3f(a, b, c); }

__global__ __launch_bounds__(256) void median3x3_kernel(const float* __restrict__ in,
                                                        float* __restrict__ out) {
    __shared__ float tile[LDS_ELEMS];

    int bid   = blockIdx.x;
    int sblk  = bid & (STRIPS - 1);
    int plane = bid >> 5;            // 96 planes
    int tid   = threadIdx.x;

    int ybase = sblk * TR;
    const float* pbase = in + (size_t)plane * (H * W);

    // ---- stage 18 rows into LDS: 9 rounds x (256 threads x 16 B) ----
    // Per round, each wave's 64 lanes cover a contiguous 1 KB segment that
    // lies entirely within one tile row (chunks are 256-element aligned).
#pragma unroll
    for (int k = 0; k < STAGE_ROUNDS; ++k) {
        int e   = k * 1024 + tid * 4;          // element index in tile
        int lr  = e >> 9;                      // tile row 0..17
        int col = e & (W - 1);
        int gy  = ybase - 1 + lr;
        int gyc = min(max(gy, 0), H - 1);      // clamp; zero-fixed at consume
        const float* src = pbase + (size_t)gyc * W + col;
        // LDS dest: wave-uniform base + lane*16 (linear layout, no padding)
        float* dst = &tile[k * 1024 + (tid & 192) * 4];
        __builtin_amdgcn_global_load_lds((const unsigned int*)src,
                                         (unsigned int*)dst, 16, 0, 0);
    }
    __syncthreads();   // drains vmcnt(0) before any wave reads the tile

    // ---- compute: thread = 4 cols x 8 rows ----
    int rsel = tid >> 7;                 // 0: tile rows 0..9, 1: tile rows 8..17
    int x0   = (tid & 127) << 2;
    int lr0  = rsel * 8;
    bool zTop = (sblk == 0) && (rsel == 0);            // tile row 0  is gy=-1
    bool zBot = (sblk == STRIPS - 1) && (rsel == 1);   // tile row 17 is gy=H

    // rolling sorted-triple window; [3] indices are compile-time under unroll
    float Lw[3][4], Mw[3][4], Hw[3][4];

    auto loadrow = [&](int lr, bool zero, float* l, float* m, float* h) {
        const float* rowp = &tile[lr * W];
        float4 c  = *(const float4*)(rowp + x0);
        float  lf = rowp[(x0 == 0) ? 0 : (x0 - 1)];        // clamped addr
        float  rg = rowp[(x0 == W - 4) ? (W - 1) : (x0 + 4)];
        if (x0 == 0)     lf = 0.0f;                        // true zero-pad
        if (x0 == W - 4) rg = 0.0f;
        if (zero) { c = make_float4(0.f, 0.f, 0.f, 0.f); lf = 0.f; rg = 0.f; }
        float p0 = lf, p1 = c.x, p2 = c.y, p3 = c.z, p4 = c.w, p5 = rg;
        l[0] = f_min3(p0, p1, p2); m[0] = f_med3(p0, p1, p2); h[0] = f_max3(p0, p1, p2);
        l[1] = f_min3(p1, p2, p3); m[1] = f_med3(p1, p2, p3); h[1] = f_max3(p1, p2, p3);
        l[2] = f_min3(p2, p3, p4); m[2] = f_med3(p2, p3, p4); h[2] = f_max3(p2, p3, p4);
        l[3] = f_min3(p3, p4, p5); m[3] = f_med3(p3, p4, p5); h[3] = f_max3(p3, p4, p5);
    };

    loadrow(lr0,     zTop,  Lw[0], Mw[0], Hw[0]);
    loadrow(lr0 + 1, false, Lw[1], Mw[1], Hw[1]);

    float* obase = out + (size_t)plane * (H * W) + (size_t)(ybase + rsel * 8) * W + x0;
#pragma unroll
    for (int r = 0; r < 8; ++r) {
        bool zl = zBot && (r == 7);          // loading tile row 17
        loadrow(lr0 + r + 2, zl, Lw[(r + 2) % 3], Mw[(r + 2) % 3], Hw[(r + 2) % 3]);
        float res[4];
#pragma unroll
        for (int j = 0; j < 4; ++j) {
            float lo = f_max3(Lw[r % 3][j], Lw[(r + 1) % 3][j], Lw[(r + 2) % 3][j]);
            float mi = f_med3(Mw[r % 3][j], Mw[(r + 1) % 3][j], Mw[(r + 2) % 3][j]);
            float hi = f_min3(Hw[r % 3][j], Hw[(r + 1) % 3][j], Hw[(r + 2) % 3][j]);
            res[j] = f_med3(lo, mi, hi);
        }
        *(float4*)(obase + (size_t)r * W) = make_float4(res[0], res[1], res[2], res[3]);
    }
}

extern "C" void kernel_launch(void* const* d_in, const int* in_sizes, int n_in,
                              void* d_out, int out_size, void* d_ws, size_t ws_size,
                              hipStream_t stream) {
    const float* x = (const float*)d_in[0];
    float* out = (float*)d_out;

    // 96 planes x 32 strips of 16 rows = 3072 blocks; 256 thr: 4 cols x 8 rows each.
    int blocks = (out_size / (H * W)) * STRIPS;   // 3072
    median3x3_kernel<<<dim3(blocks), dim3(256), 0, stream>>>(x, out);
}